// Round 6
// baseline (453.897 us; speedup 1.0000x reference)
//
#include <hip/hip_runtime.h>

#define B_  4
#define C_  512
#define CQ_ 64
#define N_  4096
#define LOG2E 1.44269504088896f

typedef _Float16 half8 __attribute__((ext_vector_type(8)));
typedef _Float16 half4 __attribute__((ext_vector_type(4)));
typedef float    f32x4 __attribute__((ext_vector_type(4)));

// ---------------------------------------------------------------------------
// Kernel 1: fused QKV projection.  Out(ch, n) = W(ch, c) * x(c, n) per batch.
// Q scaled by log2(e) (softmax done in exp2 domain).
// Q, K stored n-major: Qh[b][n][cq];  V stored d-major: Vh[b][d][m]
// ---------------------------------------------------------------------------
__global__ __launch_bounds__(256) void proj_kernel(
    const float* __restrict__ x,  const float* __restrict__ Wq,
    const float* __restrict__ Wk, const float* __restrict__ Wv,
    _Float16* __restrict__ Qh, _Float16* __restrict__ Kh, _Float16* __restrict__ Vh)
{
  __shared__ _Float16 As[64][40];
  __shared__ _Float16 Bs[64][40];

  const int tid = threadIdx.x;
  const int wid = tid >> 6, lane = tid & 63, ln = lane & 15, lh = lane >> 4;
  const int nBase  = blockIdx.x * 64;
  const int chTile = blockIdx.y;
  const int b      = blockIdx.z;

  const float* Wsrc;
  if (chTile == 0)      Wsrc = Wq;
  else if (chTile == 1) Wsrc = Wk;
  else                  Wsrc = Wv + (size_t)(chTile - 2) * 64 * C_;

  f32x4 acc[4] = {};

  const int ar = tid >> 2, ac = (tid & 3) * 8;
  const int bc = tid >> 3, bn = (tid & 7) * 8;

  for (int kt = 0; kt < C_; kt += 32) {
    __syncthreads();
    {
      const float* src = Wsrc + (size_t)ar * C_ + kt + ac;
      #pragma unroll
      for (int u = 0; u < 8; ++u) As[ar][ac + u] = (_Float16)src[u];
    }
    {
      const float* src = x + ((size_t)b * C_ + kt + bc) * N_ + nBase + bn;
      #pragma unroll
      for (int u = 0; u < 8; ++u) Bs[bn + u][bc] = (_Float16)src[u];
    }
    __syncthreads();
    half8 a = *(const half8*)&As[wid * 16 + ln][lh * 8];
    #pragma unroll
    for (int ct = 0; ct < 4; ++ct) {
      half8 bf = *(const half8*)&Bs[ct * 16 + ln][lh * 8];
      acc[ct] = __builtin_amdgcn_mfma_f32_16x16x32_f16(a, bf, acc[ct], 0, 0, 0);
    }
  }

  #pragma unroll
  for (int ct = 0; ct < 4; ++ct) {
    const int n = nBase + ct * 16 + ln;
    #pragma unroll
    for (int j = 0; j < 4; ++j) {
      const int chL = wid * 16 + lh * 4 + j;
      if (chTile == 0)
        Qh[((size_t)b * N_ + n) * CQ_ + chL] = (_Float16)(acc[ct][j] * LOG2E);
      else if (chTile == 1)
        Kh[((size_t)b * N_ + n) * CQ_ + chL] = (_Float16)acc[ct][j];
      else
        Vh[((size_t)b * C_ + (chTile - 2) * 64 + chL) * N_ + n] = (_Float16)acc[ct][j];
    }
  }
}

// ---------------------------------------------------------------------------
// Kernel 2: exact per-row max of E (log2 domain; Q pre-scaled by log2e).
// Block = (b, 64 queries), 8 waves; wave w scans keys {it*128 + w*16 + ...}.
// Swapped MFMA (A=K, B=Q): thread's e values all belong to query (lane&15).
// Zero barriers in the loop; one LDS merge at the end. MFMA sequence is
// bitwise-identical to the main kernel's QK, so e - m <= 0 exactly.
// ---------------------------------------------------------------------------
__global__ __launch_bounds__(512) void stats_kernel(
    const _Float16* __restrict__ Qh, const _Float16* __restrict__ Kh,
    float* __restrict__ m_g)
{
  __shared__ float Ms[8][64];

  const int tid = threadIdx.x;
  const int wid = tid >> 6, lane = tid & 63, ln = lane & 15, lh = lane >> 4;
  const int b  = blockIdx.x >> 6;
  const int qb = (blockIdx.x & 63) * 64;

  half8 qf[4][2];
  #pragma unroll
  for (int rt = 0; rt < 4; ++rt)
    #pragma unroll
    for (int h = 0; h < 2; ++h)
      qf[rt][h] = *(const half8*)&Qh[((size_t)b * N_ + qb + rt * 16 + ln) * CQ_ + h * 32 + lh * 8];

  f32x4 vmax[4];
  #pragma unroll
  for (int rt = 0; rt < 4; ++rt)
    #pragma unroll
    for (int j = 0; j < 4; ++j) vmax[rt][j] = -3.0e38f;

  const _Float16* kp = Kh + ((size_t)b * N_ + wid * 16 + ln) * CQ_ + lh * 8;

  for (int it = 0; it < 32; ++it) {
    const _Float16* kq = kp + (size_t)(it * 128) * CQ_;
    half8 k0 = *(const half8*)kq;
    half8 k1 = *(const half8*)(kq + 32);
    #pragma unroll
    for (int rt = 0; rt < 4; ++rt) {
      f32x4 e = {};
      e = __builtin_amdgcn_mfma_f32_16x16x32_f16(k0, qf[rt][0], e, 0, 0, 0);
      e = __builtin_amdgcn_mfma_f32_16x16x32_f16(k1, qf[rt][1], e, 0, 0, 0);
      #pragma unroll
      for (int j = 0; j < 4; ++j) vmax[rt][j] = fmaxf(vmax[rt][j], e[j]);
    }
  }

  #pragma unroll
  for (int rt = 0; rt < 4; ++rt) {
    float mj = fmaxf(fmaxf(vmax[rt][0], vmax[rt][1]), fmaxf(vmax[rt][2], vmax[rt][3]));
    mj = fmaxf(mj, __shfl_xor(mj, 16));
    mj = fmaxf(mj, __shfl_xor(mj, 32));
    if (lane < 16) Ms[wid][rt * 16 + lane] = mj;
  }
  __syncthreads();
  if (tid < 64) {
    float m = Ms[0][tid];
    #pragma unroll
    for (int w = 1; w < 8; ++w) m = fmaxf(m, Ms[w][tid]);
    m_g[(size_t)b * N_ + qb + tid] = m;
  }
}

// ---------------------------------------------------------------------------
// Kernel 3: attention main pass. Block = (b, d-quarter 128ch, 32 queries),
// 4 waves; wave w owns key strip {it*128 + w*32 .. +31} for ALL 128 d.
// Swapped QK -> P is wave-local -> 2KB wave-private LDS tile (no barriers!)
// -> PV MFMA accumulates partial acc; waves merged once at the end.
// P = exp2(e - m_row) in (0,1]; l summed per-thread, divided in epilogue.
// ---------------------------------------------------------------------------
__global__ __launch_bounds__(256) void attn_kernel(
    const float* __restrict__ x, const _Float16* __restrict__ Qh,
    const _Float16* __restrict__ Kh, const _Float16* __restrict__ Vh,
    const float* __restrict__ m_g, const float* __restrict__ gamma,
    float* __restrict__ out)
{
  __shared__ _Float16 Ptile[4][32][32];   // 8 KB, wave-private [wid]
  __shared__ float    Red[3][64][8];      // 6 KB, end-of-kernel acc merge
  __shared__ float    Lp[4][32];

  const int tid = threadIdx.x;
  const int wid = tid >> 6, lane = tid & 63, ln = lane & 15, lh = lane >> 4;

  // bijective XCD swizzle: 2048 blocks, 256 per XCD (one b, two d-quarters)
  const int wg = (blockIdx.x & 7) * 256 + (blockIdx.x >> 3);
  const int b  = wg >> 9;
  const int dq = (wg >> 7) & 3;
  const int n0 = (wg & 127) * 32;
  const int d0 = dq * 128;

  // per-row max (log2 domain), for this thread's 2 query rows
  float m2[2];
  #pragma unroll
  for (int rt = 0; rt < 2; ++rt)
    m2[rt] = m_g[(size_t)b * N_ + n0 + rt * 16 + ln];

  // persistent Q fragments (B-operand: col=query, k=cq)
  half8 qf[2][2];
  #pragma unroll
  for (int rt = 0; rt < 2; ++rt)
    #pragma unroll
    for (int h = 0; h < 2; ++h)
      qf[rt][h] = *(const half8*)&Qh[((size_t)b * N_ + n0 + rt * 16 + ln) * CQ_ + h * 32 + lh * 8];

  f32x4 acc[8][2] = {};
  float lsum[2] = {0.f, 0.f};

  const _Float16* kp = Kh + ((size_t)b * N_ + wid * 32 + ln) * CQ_ + lh * 8;
  const _Float16* vp = Vh + ((size_t)(b * C_ + d0) + ln) * (size_t)N_ + wid * 32 + lh * 8;
  _Float16* Pw = &Ptile[wid][0][0];

  // P store geometry: row q=rt*16+ln, keys kt*16+lh*4+{0..3}
  // chunk = kt*2+(lh>>1), swizzled: chunk ^= (q&3)  [16B chunks]
  const int pst0 = ln * 32 + ((lh & 1) << 2);      // + ((kt*2+(lh>>1))^(ln&3))<<3
  const int prd0 = ln * 32 + ((lh ^ (ln & 3)) << 3);

  for (int it = 0; it < 32; ++it) {
    const size_t koff = (size_t)it * 128 * CQ_;
    const int    moff = it * 128;

    // K fragments (A-operand: row=key, k=cq)
    half8 kf00 = *(const half8*)(kp + koff);
    half8 kf01 = *(const half8*)(kp + koff + 32);
    half8 kf10 = *(const half8*)(kp + koff + 16 * CQ_);
    half8 kf11 = *(const half8*)(kp + koff + 16 * CQ_ + 32);

    // V fragments dt 0..3 (A-operand: row=d, k=key) — issue early
    half8 vfa[4];
    #pragma unroll
    for (int dt = 0; dt < 4; ++dt)
      vfa[dt] = *(const half8*)(vp + (size_t)dt * 16 * N_ + moff);

    // ---- QK (swapped): e[kt][rt], col=query, row=key
    f32x4 e[2][2];
    #pragma unroll
    for (int rt = 0; rt < 2; ++rt) {
      e[0][rt] = (f32x4){};
      e[0][rt] = __builtin_amdgcn_mfma_f32_16x16x32_f16(kf00, qf[rt][0], e[0][rt], 0, 0, 0);
      e[0][rt] = __builtin_amdgcn_mfma_f32_16x16x32_f16(kf01, qf[rt][1], e[0][rt], 0, 0, 0);
      e[1][rt] = (f32x4){};
      e[1][rt] = __builtin_amdgcn_mfma_f32_16x16x32_f16(kf10, qf[rt][0], e[1][rt], 0, 0, 0);
      e[1][rt] = __builtin_amdgcn_mfma_f32_16x16x32_f16(kf11, qf[rt][1], e[1][rt], 0, 0, 0);
    }

    // ---- P = exp2(e - m) -> wave-private LDS (no barrier!)
    #pragma unroll
    for (int kt = 0; kt < 2; ++kt)
      #pragma unroll
      for (int rt = 0; rt < 2; ++rt) {
        half4 pv;
        #pragma unroll
        for (int j = 0; j < 4; ++j) {
          const float p = exp2f(e[kt][rt][j] - m2[rt]);
          lsum[rt] += p;
          pv[j] = (_Float16)p;
        }
        const int chunk = ((kt * 2 + (lh >> 1)) ^ (ln & 3)) << 3;
        *(half4*)(Pw + rt * 512 + pst0 + chunk) = pv;
      }

    // V fragments dt 4..7 — issue while P settles
    half8 vfb[4];
    #pragma unroll
    for (int dt = 0; dt < 4; ++dt)
      vfb[dt] = *(const half8*)(vp + (size_t)(dt + 4) * 16 * N_ + moff);

    // ---- P read (B-operand: col=query, k=key 0..31)
    half8 pf[2];
    #pragma unroll
    for (int rt = 0; rt < 2; ++rt)
      pf[rt] = *(const half8*)(Pw + rt * 512 + prd0);

    // ---- PV
    __builtin_amdgcn_s_setprio(1);
    #pragma unroll
    for (int dt = 0; dt < 4; ++dt) {
      acc[dt][0] = __builtin_amdgcn_mfma_f32_16x16x32_f16(vfa[dt], pf[0], acc[dt][0], 0, 0, 0);
      acc[dt][1] = __builtin_amdgcn_mfma_f32_16x16x32_f16(vfa[dt], pf[1], acc[dt][1], 0, 0, 0);
    }
    #pragma unroll
    for (int dt = 0; dt < 4; ++dt) {
      acc[dt + 4][0] = __builtin_amdgcn_mfma_f32_16x16x32_f16(vfb[dt], pf[0], acc[dt + 4][0], 0, 0, 0);
      acc[dt + 4][1] = __builtin_amdgcn_mfma_f32_16x16x32_f16(vfb[dt], pf[1], acc[dt + 4][1], 0, 0, 0);
    }
    __builtin_amdgcn_s_setprio(0);
  }

  // ---- l: reduce over lh lanes, publish per-wave partials
  #pragma unroll
  for (int rt = 0; rt < 2; ++rt) {
    lsum[rt] += __shfl_xor(lsum[rt], 16);
    lsum[rt] += __shfl_xor(lsum[rt], 32);
  }
  if (lane < 16) { Lp[wid][lane] = lsum[0]; Lp[wid][16 + lane] = lsum[1]; }

  // ---- merge acc across the 4 key-strip waves; wave 0 writes output
  const float g = gamma[0];
  float linv[2];
  #pragma unroll
  for (int dt = 0; dt < 8; ++dt) {
    __syncthreads();
    if (wid) {
      float* dst = &Red[wid - 1][lane][0];
      *(f32x4*)dst       = acc[dt][0];
      *(f32x4*)(dst + 4) = acc[dt][1];
    }
    __syncthreads();
    if (wid == 0) {
      if (dt == 0) {
        #pragma unroll
        for (int rt = 0; rt < 2; ++rt) {
          const int q = rt * 16 + ln;
          linv[rt] = 1.0f / (Lp[0][q] + Lp[1][q] + Lp[2][q] + Lp[3][q]);
        }
      }
      #pragma unroll
      for (int w = 0; w < 3; ++w) {
        acc[dt][0] += *(const f32x4*)&Red[w][lane][0];
        acc[dt][1] += *(const f32x4*)&Red[w][lane][4];
      }
      #pragma unroll
      for (int j = 0; j < 4; ++j) {
        const size_t row = ((size_t)b * C_ + d0 + dt * 16 + lh * 4 + j) * N_ + n0;
        out[row + ln]      = g * acc[dt][0][j] * linv[0] + x[row + ln];
        out[row + 16 + ln] = g * acc[dt][1][j] * linv[1] + x[row + 16 + ln];
      }
    }
  }
}

extern "C" void kernel_launch(void* const* d_in, const int* in_sizes, int n_in,
                              void* d_out, int out_size, void* d_ws, size_t ws_size,
                              hipStream_t stream) {
  const float* x     = (const float*)d_in[0];
  const float* Wq    = (const float*)d_in[1];
  const float* Wk    = (const float*)d_in[2];
  const float* Wv    = (const float*)d_in[3];
  const float* gamma = (const float*)d_in[4];
  float* out = (float*)d_out;

  _Float16* Qh = (_Float16*)d_ws;                       // 2 MB
  _Float16* Kh = Qh + (size_t)B_ * N_ * CQ_;            // 2 MB
  _Float16* Vh = Kh + (size_t)B_ * N_ * CQ_;            // 16.8 MB
  float* m_g  = (float*)(Vh + (size_t)B_ * C_ * N_);    // 64 KB

  proj_kernel<<<dim3(64, 10, B_), 256, 0, stream>>>(x, Wq, Wk, Wv, Qh, Kh, Vh);
  stats_kernel<<<dim3(256), 512, 0, stream>>>(Qh, Kh, m_g);
  attn_kernel<<<dim3(2048), 256, 0, stream>>>(x, Qh, Kh, Vh, m_g, gamma, out);
}

// Round 7
// 364.673 us; speedup vs baseline: 1.2447x; 1.2447x over previous
//
#include <hip/hip_runtime.h>

#define B_  4
#define C_  512
#define CQ_ 64
#define N_  4096
#define LOG2E 1.44269504088896f

typedef _Float16 half8 __attribute__((ext_vector_type(8)));
typedef _Float16 half4 __attribute__((ext_vector_type(4)));
typedef float    f32x4 __attribute__((ext_vector_type(4)));

// ---------------------------------------------------------------------------
// Kernel 1: fused QKV projection.  Out(ch, n) = W(ch, c) * x(c, n) per batch.
// Q scaled by log2(e) (softmax done in exp2 domain).
// Q, K stored n-major: Qh[b][n][cq];  V stored d-major: Vh[b][d][m]
// ---------------------------------------------------------------------------
__global__ __launch_bounds__(256) void proj_kernel(
    const float* __restrict__ x,  const float* __restrict__ Wq,
    const float* __restrict__ Wk, const float* __restrict__ Wv,
    _Float16* __restrict__ Qh, _Float16* __restrict__ Kh, _Float16* __restrict__ Vh)
{
  __shared__ _Float16 As[64][40];
  __shared__ _Float16 Bs[64][40];

  const int tid = threadIdx.x;
  const int wid = tid >> 6, lane = tid & 63, ln = lane & 15, lh = lane >> 4;
  const int nBase  = blockIdx.x * 64;
  const int chTile = blockIdx.y;
  const int b      = blockIdx.z;

  const float* Wsrc;
  if (chTile == 0)      Wsrc = Wq;
  else if (chTile == 1) Wsrc = Wk;
  else                  Wsrc = Wv + (size_t)(chTile - 2) * 64 * C_;

  f32x4 acc[4] = {};

  const int ar = tid >> 2, ac = (tid & 3) * 8;
  const int bc = tid >> 3, bn = (tid & 7) * 8;

  for (int kt = 0; kt < C_; kt += 32) {
    __syncthreads();
    {
      const float* src = Wsrc + (size_t)ar * C_ + kt + ac;
      #pragma unroll
      for (int u = 0; u < 8; ++u) As[ar][ac + u] = (_Float16)src[u];
    }
    {
      const float* src = x + ((size_t)b * C_ + kt + bc) * N_ + nBase + bn;
      #pragma unroll
      for (int u = 0; u < 8; ++u) Bs[bn + u][bc] = (_Float16)src[u];
    }
    __syncthreads();
    half8 a = *(const half8*)&As[wid * 16 + ln][lh * 8];
    #pragma unroll
    for (int ct = 0; ct < 4; ++ct) {
      half8 bf = *(const half8*)&Bs[ct * 16 + ln][lh * 8];
      acc[ct] = __builtin_amdgcn_mfma_f32_16x16x32_f16(a, bf, acc[ct], 0, 0, 0);
    }
  }

  #pragma unroll
  for (int ct = 0; ct < 4; ++ct) {
    const int n = nBase + ct * 16 + ln;
    #pragma unroll
    for (int j = 0; j < 4; ++j) {
      const int chL = wid * 16 + lh * 4 + j;
      if (chTile == 0)
        Qh[((size_t)b * N_ + n) * CQ_ + chL] = (_Float16)(acc[ct][j] * LOG2E);
      else if (chTile == 1)
        Kh[((size_t)b * N_ + n) * CQ_ + chL] = (_Float16)acc[ct][j];
      else
        Vh[((size_t)b * C_ + (chTile - 2) * 64 + chL) * N_ + n] = (_Float16)acc[ct][j];
    }
  }
}

// ---------------------------------------------------------------------------
// Kernel 2: exact per-row max of E (log2 domain; Q pre-scaled by log2e).
// Block = (b, 64 queries), 8 waves; wave w scans keys {it*128 + w*16 + ...}.
// Swapped MFMA (A=K, B=Q). MFMA fragment pattern and chaining are bitwise-
// identical to the main kernel's QK, so e - m <= 0 exactly there.
// ---------------------------------------------------------------------------
__global__ __launch_bounds__(512) void stats_kernel(
    const _Float16* __restrict__ Qh, const _Float16* __restrict__ Kh,
    float* __restrict__ m_g)
{
  __shared__ float Ms[8][64];

  const int tid = threadIdx.x;
  const int wid = tid >> 6, lane = tid & 63, ln = lane & 15, lh = lane >> 4;
  const int b  = blockIdx.x >> 6;
  const int qb = (blockIdx.x & 63) * 64;

  half8 qf[4][2];
  #pragma unroll
  for (int rt = 0; rt < 4; ++rt)
    #pragma unroll
    for (int h = 0; h < 2; ++h)
      qf[rt][h] = *(const half8*)&Qh[((size_t)b * N_ + qb + rt * 16 + ln) * CQ_ + h * 32 + lh * 8];

  f32x4 vmax[4];
  #pragma unroll
  for (int rt = 0; rt < 4; ++rt)
    #pragma unroll
    for (int j = 0; j < 4; ++j) vmax[rt][j] = -3.0e38f;

  const _Float16* kp = Kh + ((size_t)b * N_ + wid * 16 + ln) * CQ_ + lh * 8;

  for (int it = 0; it < 32; ++it) {
    const _Float16* kq = kp + (size_t)(it * 128) * CQ_;
    half8 k0 = *(const half8*)kq;
    half8 k1 = *(const half8*)(kq + 32);
    #pragma unroll
    for (int rt = 0; rt < 4; ++rt) {
      f32x4 e = {};
      e = __builtin_amdgcn_mfma_f32_16x16x32_f16(k0, qf[rt][0], e, 0, 0, 0);
      e = __builtin_amdgcn_mfma_f32_16x16x32_f16(k1, qf[rt][1], e, 0, 0, 0);
      #pragma unroll
      for (int j = 0; j < 4; ++j) vmax[rt][j] = fmaxf(vmax[rt][j], e[j]);
    }
  }

  #pragma unroll
  for (int rt = 0; rt < 4; ++rt) {
    float mj = fmaxf(fmaxf(vmax[rt][0], vmax[rt][1]), fmaxf(vmax[rt][2], vmax[rt][3]));
    mj = fmaxf(mj, __shfl_xor(mj, 16));
    mj = fmaxf(mj, __shfl_xor(mj, 32));
    if (lane < 16) Ms[wid][rt * 16 + lane] = mj;
  }
  __syncthreads();
  if (tid < 64) {
    float m = Ms[0][tid];
    #pragma unroll
    for (int w = 1; w < 8; ++w) m = fmaxf(m, Ms[w][tid]);
    m_g[(size_t)b * N_ + qb + tid] = m;
  }
}

// ---------------------------------------------------------------------------
// Kernel 3: attention main pass (redundancy-free).
// Block = (b, 32 queries), 8 waves (512 thr); wave w owns d [w*64, w*64+64)
// AND key slice {it*128 + w*16 .. +16} of each 128-key iteration.
// Swapped QK (A=K,B=Q) -> each wave's e slice -> P = exp2(e-m) -> single
// 8 KB swizzled LDS tile -> barrier -> all waves read full 128-key P ->
// PV MFMA for their d. 2 barriers/iter. K prefetched 1 iter ahead; V rolled.
// ---------------------------------------------------------------------------
__global__ __launch_bounds__(512) void attn_kernel(
    const float* __restrict__ x, const _Float16* __restrict__ Qh,
    const _Float16* __restrict__ Kh, const _Float16* __restrict__ Vh,
    const float* __restrict__ m_g, const float* __restrict__ gamma,
    float* __restrict__ out)
{
  __shared__ _Float16 Ps[32 * 128];   // [q][key] fp16, 16B-chunk swizzle, 8 KB
  __shared__ float    Lp[8][32];

  const int tid = threadIdx.x;
  const int wid = tid >> 6, lane = tid & 63, ln = lane & 15, lh = lane >> 4;

  // bijective XCD swizzle: 512 blocks, 64 consecutive (same-b) wg per XCD
  const int wg = (blockIdx.x & 7) * 64 + (blockIdx.x >> 3);
  const int b  = wg >> 7;
  const int n0 = (wg & 127) * 32;
  const int d0w = wid * 64;

  // exact per-row max (log2 domain) for this lane's two query columns
  const float m20 = m_g[(size_t)b * N_ + n0 + ln];
  const float m21 = m_g[(size_t)b * N_ + n0 + 16 + ln];

  // persistent Q fragments (B-operand: col=query, k=cq)
  half8 qf[2][2];
  #pragma unroll
  for (int rt = 0; rt < 2; ++rt)
    #pragma unroll
    for (int h = 0; h < 2; ++h)
      qf[rt][h] = *(const half8*)&Qh[((size_t)b * N_ + n0 + rt * 16 + ln) * CQ_ + h * 32 + lh * 8];

  // K (A-operand: row=key, k=cq): wave's slice = it*128 + wid*16 + ln
  const _Float16* kp = Kh + ((size_t)b * N_ + (wid << 4) + ln) * CQ_ + (lh << 3);
  half8 kf0 = *(const half8*)kp;
  half8 kf1 = *(const half8*)(kp + 32);

  // V (A-operand: row=d, k=key): rows d0w + dt*16 + ln
  const _Float16* vbase = Vh + ((size_t)b * C_ + d0w + ln) * (size_t)N_ + (lh << 3);

  f32x4 acc[4][2] = {};
  float lsum0 = 0.f, lsum1 = 0.f;

  const int cstore = ((wid << 1) | (lh >> 1)) ^ (ln & 7);   // swizzled 16B chunk
  const int hoff   = (lh & 1) << 2;                          // half4 within chunk
  const int swr    = ln & 7;

  for (int it = 0; it < 32; ++it) {
    const int moff = it << 7;

    // ---- Phase 1: QK (swapped) for this wave's 16-key slice; P -> LDS
    f32x4 e0 = {}, e1 = {};
    e0 = __builtin_amdgcn_mfma_f32_16x16x32_f16(kf0, qf[0][0], e0, 0, 0, 0);
    e0 = __builtin_amdgcn_mfma_f32_16x16x32_f16(kf1, qf[0][1], e0, 0, 0, 0);
    e1 = __builtin_amdgcn_mfma_f32_16x16x32_f16(kf0, qf[1][0], e1, 0, 0, 0);
    e1 = __builtin_amdgcn_mfma_f32_16x16x32_f16(kf1, qf[1][1], e1, 0, 0, 0);

    {
      half4 pv0, pv1;
      #pragma unroll
      for (int j = 0; j < 4; ++j) {
        const float p0 = exp2f(e0[j] - m20);
        const float p1 = exp2f(e1[j] - m21);
        lsum0 += p0;  lsum1 += p1;
        pv0[j] = (_Float16)p0;  pv1[j] = (_Float16)p1;
      }
      *(half4*)&Ps[(ln)      * 128 + (cstore << 3) + hoff] = pv0;
      *(half4*)&Ps[(16 + ln) * 128 + (cstore << 3) + hoff] = pv1;
    }
    __syncthreads();

    // ---- Phase 2: prefetch next K; read full P; PV MFMA (V rolled 2-deep)
    const int itn = ((it + 1) & 31) << 7;
    half8 kn0 = *(const half8*)(kp + (size_t)itn * CQ_);
    half8 kn1 = *(const half8*)(kp + (size_t)itn * CQ_ + 32);

    half8 pf[2][4];
    #pragma unroll
    for (int nt = 0; nt < 2; ++nt)
      #pragma unroll
      for (int kk = 0; kk < 4; ++kk)
        pf[nt][kk] = *(const half8*)&Ps[(nt * 16 + ln) * 128 + ((((kk << 2) | lh) ^ swr) << 3)];

    const _Float16* vp = vbase + moff;
    half8 va[4], vb[4];
    #pragma unroll
    for (int kk = 0; kk < 4; ++kk) va[kk] = *(const half8*)(vp + (kk << 5));
    #pragma unroll
    for (int kk = 0; kk < 4; ++kk) vb[kk] = *(const half8*)(vp + (size_t)16 * N_ + (kk << 5));

    // dt = 0 (va), then reload va with dt=2
    #pragma unroll
    for (int nt = 0; nt < 2; ++nt)
      #pragma unroll
      for (int kk = 0; kk < 4; ++kk)
        acc[0][nt] = __builtin_amdgcn_mfma_f32_16x16x32_f16(va[kk], pf[nt][kk], acc[0][nt], 0, 0, 0);
    #pragma unroll
    for (int kk = 0; kk < 4; ++kk) va[kk] = *(const half8*)(vp + (size_t)32 * N_ + (kk << 5));

    // dt = 1 (vb), then reload vb with dt=3
    #pragma unroll
    for (int nt = 0; nt < 2; ++nt)
      #pragma unroll
      for (int kk = 0; kk < 4; ++kk)
        acc[1][nt] = __builtin_amdgcn_mfma_f32_16x16x32_f16(vb[kk], pf[nt][kk], acc[1][nt], 0, 0, 0);
    #pragma unroll
    for (int kk = 0; kk < 4; ++kk) vb[kk] = *(const half8*)(vp + (size_t)48 * N_ + (kk << 5));

    // dt = 2 (va)
    #pragma unroll
    for (int nt = 0; nt < 2; ++nt)
      #pragma unroll
      for (int kk = 0; kk < 4; ++kk)
        acc[2][nt] = __builtin_amdgcn_mfma_f32_16x16x32_f16(va[kk], pf[nt][kk], acc[2][nt], 0, 0, 0);

    // dt = 3 (vb)
    #pragma unroll
    for (int nt = 0; nt < 2; ++nt)
      #pragma unroll
      for (int kk = 0; kk < 4; ++kk)
        acc[3][nt] = __builtin_amdgcn_mfma_f32_16x16x32_f16(vb[kk], pf[nt][kk], acc[3][nt], 0, 0, 0);

    kf0 = kn0;  kf1 = kn1;
    __syncthreads();
  }

  // ---- softmax denominators: reduce over the 4 lh groups, then 8 waves
  lsum0 += __shfl_xor(lsum0, 16);
  lsum0 += __shfl_xor(lsum0, 32);
  lsum1 += __shfl_xor(lsum1, 16);
  lsum1 += __shfl_xor(lsum1, 32);
  if (lane < 16) { Lp[wid][lane] = lsum0; Lp[wid][16 + lane] = lsum1; }
  __syncthreads();

  float linv[2];
  #pragma unroll
  for (int nt = 0; nt < 2; ++nt) {
    const int q = nt * 16 + ln;
    float s = Lp[0][q];
    #pragma unroll
    for (int w = 1; w < 8; ++w) s += Lp[w][q];
    linv[nt] = 1.0f / s;
  }

  const float g = gamma[0];
  #pragma unroll
  for (int dt = 0; dt < 4; ++dt) {
    #pragma unroll
    for (int j = 0; j < 4; ++j) {
      const size_t row = ((size_t)b * C_ + d0w + dt * 16 + lh * 4 + j) * N_ + n0;
      out[row + ln]      = g * acc[dt][0][j] * linv[0] + x[row + ln];
      out[row + 16 + ln] = g * acc[dt][1][j] * linv[1] + x[row + 16 + ln];
    }
  }
}

extern "C" void kernel_launch(void* const* d_in, const int* in_sizes, int n_in,
                              void* d_out, int out_size, void* d_ws, size_t ws_size,
                              hipStream_t stream) {
  const float* x     = (const float*)d_in[0];
  const float* Wq    = (const float*)d_in[1];
  const float* Wk    = (const float*)d_in[2];
  const float* Wv    = (const float*)d_in[3];
  const float* gamma = (const float*)d_in[4];
  float* out = (float*)d_out;

  _Float16* Qh = (_Float16*)d_ws;                       // 2 MB
  _Float16* Kh = Qh + (size_t)B_ * N_ * CQ_;            // 2 MB
  _Float16* Vh = Kh + (size_t)B_ * N_ * CQ_;            // 16.8 MB
  float* m_g  = (float*)(Vh + (size_t)B_ * C_ * N_);    // 64 KB

  proj_kernel<<<dim3(64, 10, B_), 256, 0, stream>>>(x, Wq, Wk, Wv, Qh, Kh, Vh);
  stats_kernel<<<dim3(256), 512, 0, stream>>>(Qh, Kh, m_g);
  attn_kernel<<<dim3(512), 512, 0, stream>>>(x, Qh, Kh, Vh, m_g, gamma, out);
}

// Round 8
// 350.788 us; speedup vs baseline: 1.2939x; 1.0396x over previous
//
#include <hip/hip_runtime.h>

#define B_  4
#define C_  512
#define CQ_ 64
#define N_  4096
#define LOG2E 1.44269504088896f

typedef _Float16 half8 __attribute__((ext_vector_type(8)));
typedef _Float16 half4 __attribute__((ext_vector_type(4)));
typedef float    f32x4 __attribute__((ext_vector_type(4)));

// async global->LDS, 16B per lane; LDS dest = wave-uniform base + lane*16
__device__ __forceinline__ void g2l16(const void* g, void* l) {
  __builtin_amdgcn_global_load_lds(
      (const __attribute__((address_space(1))) void*)g,
      (__attribute__((address_space(3))) void*)l, 16, 0, 0);
}

// ---------------------------------------------------------------------------
// Kernel 1: fused QKV projection (unchanged, verified).  Q scaled by log2e.
// Qh[b][n][cq], Kh[b][n][cq], Vh[b][d][m]
// ---------------------------------------------------------------------------
__global__ __launch_bounds__(256) void proj_kernel(
    const float* __restrict__ x,  const float* __restrict__ Wq,
    const float* __restrict__ Wk, const float* __restrict__ Wv,
    _Float16* __restrict__ Qh, _Float16* __restrict__ Kh, _Float16* __restrict__ Vh)
{
  __shared__ _Float16 As[64][40];
  __shared__ _Float16 Bs[64][40];

  const int tid = threadIdx.x;
  const int wid = tid >> 6, lane = tid & 63, ln = lane & 15, lh = lane >> 4;
  const int nBase  = blockIdx.x * 64;
  const int chTile = blockIdx.y;
  const int b      = blockIdx.z;

  const float* Wsrc;
  if (chTile == 0)      Wsrc = Wq;
  else if (chTile == 1) Wsrc = Wk;
  else                  Wsrc = Wv + (size_t)(chTile - 2) * 64 * C_;

  f32x4 acc[4] = {};

  const int ar = tid >> 2, ac = (tid & 3) * 8;
  const int bc = tid >> 3, bn = (tid & 7) * 8;

  for (int kt = 0; kt < C_; kt += 32) {
    __syncthreads();
    {
      const float* src = Wsrc + (size_t)ar * C_ + kt + ac;
      #pragma unroll
      for (int u = 0; u < 8; ++u) As[ar][ac + u] = (_Float16)src[u];
    }
    {
      const float* src = x + ((size_t)b * C_ + kt + bc) * N_ + nBase + bn;
      #pragma unroll
      for (int u = 0; u < 8; ++u) Bs[bn + u][bc] = (_Float16)src[u];
    }
    __syncthreads();
    half8 a = *(const half8*)&As[wid * 16 + ln][lh * 8];
    #pragma unroll
    for (int ct = 0; ct < 4; ++ct) {
      half8 bf = *(const half8*)&Bs[ct * 16 + ln][lh * 8];
      acc[ct] = __builtin_amdgcn_mfma_f32_16x16x32_f16(a, bf, acc[ct], 0, 0, 0);
    }
  }

  #pragma unroll
  for (int ct = 0; ct < 4; ++ct) {
    const int n = nBase + ct * 16 + ln;
    #pragma unroll
    for (int j = 0; j < 4; ++j) {
      const int chL = wid * 16 + lh * 4 + j;
      if (chTile == 0)
        Qh[((size_t)b * N_ + n) * CQ_ + chL] = (_Float16)(acc[ct][j] * LOG2E);
      else if (chTile == 1)
        Kh[((size_t)b * N_ + n) * CQ_ + chL] = (_Float16)acc[ct][j];
      else
        Vh[((size_t)b * C_ + (chTile - 2) * 64 + chL) * N_ + n] = (_Float16)acc[ct][j];
    }
  }
}

// ---------------------------------------------------------------------------
// Kernel 2: exact softmax stats (log2 domain): per-row max m and 1/l.
// Block = (b, 64 queries), 8 waves; wave w scans key slice {it*128+w*16+..}.
// Swapped mfma(K,Q): thread's 4 e-values = 4 keys of ONE query (lane&15).
// Online (m,s) per thread, zero barriers in loop, one LDS merge at end.
// Same 2-MFMA chain as the P-writer, so e-m <= ~0 there.
// ---------------------------------------------------------------------------
__global__ __launch_bounds__(512, 2) void stats_kernel(
    const _Float16* __restrict__ Qh, const _Float16* __restrict__ Kh,
    float* __restrict__ m_g, float* __restrict__ il_g)
{
  __shared__ float Ms[8][64];
  __shared__ float Ss[8][64];

  const int tid = threadIdx.x;
  const int wid = tid >> 6, lane = tid & 63, ln = lane & 15, lh = lane >> 4;
  const int b  = blockIdx.x >> 6;
  const int qb = (blockIdx.x & 63) * 64;

  half8 qf[4][2];
  #pragma unroll
  for (int rt = 0; rt < 4; ++rt)
    #pragma unroll
    for (int h = 0; h < 2; ++h)
      qf[rt][h] = *(const half8*)&Qh[((size_t)b * N_ + qb + rt * 16 + ln) * CQ_ + h * 32 + lh * 8];

  float mx[4] = {-3.0e38f, -3.0e38f, -3.0e38f, -3.0e38f};
  float sm[4] = {0.f, 0.f, 0.f, 0.f};

  const _Float16* kp = Kh + ((size_t)b * N_ + wid * 16 + ln) * CQ_ + lh * 8;

  for (int it = 0; it < 32; ++it) {
    const _Float16* kq = kp + (size_t)(it * 128) * CQ_;
    half8 k0 = *(const half8*)kq;
    half8 k1 = *(const half8*)(kq + 32);
    #pragma unroll
    for (int rt = 0; rt < 4; ++rt) {
      f32x4 e = {};
      e = __builtin_amdgcn_mfma_f32_16x16x32_f16(k0, qf[rt][0], e, 0, 0, 0);
      e = __builtin_amdgcn_mfma_f32_16x16x32_f16(k1, qf[rt][1], e, 0, 0, 0);
      const float m1 = fmaxf(fmaxf(e[0], e[1]), fmaxf(e[2], e[3]));
      const float mn = fmaxf(mx[rt], m1);
      sm[rt] = sm[rt] * exp2f(mx[rt] - mn)
             + exp2f(e[0] - mn) + exp2f(e[1] - mn)
             + exp2f(e[2] - mn) + exp2f(e[3] - mn);
      mx[rt] = mn;
    }
  }

  #pragma unroll
  for (int rt = 0; rt < 4; ++rt) {
    float m = mx[rt], s = sm[rt];
    #pragma unroll
    for (int mask = 16; mask <= 32; mask <<= 1) {
      const float om = __shfl_xor(m, mask);
      const float os = __shfl_xor(s, mask);
      const float mn = fmaxf(m, om);
      s = s * exp2f(m - mn) + os * exp2f(om - mn);
      m = mn;
    }
    if (lane < 16) { Ms[wid][rt * 16 + lane] = m; Ss[wid][rt * 16 + lane] = s; }
  }
  __syncthreads();
  if (tid < 64) {
    float m = Ms[0][tid], s = Ss[0][tid];
    #pragma unroll
    for (int w = 1; w < 8; ++w) {
      const float om = Ms[w][tid], os = Ss[w][tid];
      const float mn = fmaxf(m, om);
      s = s * exp2f(m - mn) + os * exp2f(om - mn);
      m = mn;
    }
    m_g[(size_t)b * N_ + qb + tid]  = m;
    il_g[(size_t)b * N_ + qb + tid] = 1.0f / s;
  }
}

// ---------------------------------------------------------------------------
// Kernel 3: P-writer.  P[bz][q][m] = exp2(e - m_q) * il_q  (fp16, normalized).
// Block = 64 q x 256 m, 4 waves (wave owns 64 m). Swapped mfma(K,Q):
// lane holds 4 consecutive m for one q -> coalesced half4 stores.
// ---------------------------------------------------------------------------
__global__ __launch_bounds__(256, 4) void pwrite_kernel(
    const _Float16* __restrict__ Qh, const _Float16* __restrict__ Kh,
    const float* __restrict__ m_g, const float* __restrict__ il_g,
    _Float16* __restrict__ P, int b0)
{
  const int tid = threadIdx.x;
  const int wid = tid >> 6, lane = tid & 63, ln = lane & 15, lh = lane >> 4;
  const int mb = blockIdx.x * 256;
  const int qb = blockIdx.y * 64;
  const int bz = blockIdx.z;
  const int b  = b0 + bz;

  float m_l[4], il_l[4];
  #pragma unroll
  for (int rt = 0; rt < 4; ++rt) {
    m_l[rt]  = m_g [(size_t)b * N_ + qb + rt * 16 + ln];
    il_l[rt] = il_g[(size_t)b * N_ + qb + rt * 16 + ln];
  }

  half8 qf[4][2];
  #pragma unroll
  for (int rt = 0; rt < 4; ++rt)
    #pragma unroll
    for (int h = 0; h < 2; ++h)
      qf[rt][h] = *(const half8*)&Qh[((size_t)b * N_ + qb + rt * 16 + ln) * CQ_ + h * 32 + lh * 8];

  half8 kf[4][2];
  #pragma unroll
  for (int ms = 0; ms < 4; ++ms)
    #pragma unroll
    for (int h = 0; h < 2; ++h)
      kf[ms][h] = *(const half8*)&Kh[((size_t)b * N_ + mb + wid * 64 + ms * 16 + ln) * CQ_ + h * 32 + lh * 8];

  #pragma unroll
  for (int ms = 0; ms < 4; ++ms) {
    #pragma unroll
    for (int rt = 0; rt < 4; ++rt) {
      f32x4 e = {};
      e = __builtin_amdgcn_mfma_f32_16x16x32_f16(kf[ms][0], qf[rt][0], e, 0, 0, 0);
      e = __builtin_amdgcn_mfma_f32_16x16x32_f16(kf[ms][1], qf[rt][1], e, 0, 0, 0);
      half4 pv;
      #pragma unroll
      for (int j = 0; j < 4; ++j)
        pv[j] = (_Float16)(exp2f(e[j] - m_l[rt]) * il_l[rt]);
      *(half4*)&P[((size_t)bz * N_ + qb + rt * 16 + ln) * N_ + mb + wid * 64 + ms * 16 + lh * 4] = pv;
    }
  }
}

// ---------------------------------------------------------------------------
// Kernel 4: PV GEMM (m97 structure).  out[b][d][n] = g * (V . P^T) + x.
// A = Vh[b][d][m] (K-contig), B^T = P[bz][n][m] (K-contig). 128x128 tile,
// BK=64, 4 waves in 2x2, double-buffered linear LDS via global_load_lds(16B),
// 2-phase loop: stage(next) -> ds_read+MFMA(cur) -> vmcnt(0) -> barrier.
// ---------------------------------------------------------------------------
__global__ __launch_bounds__(256, 2) void pv_kernel(
    const float* __restrict__ x, const _Float16* __restrict__ Vh,
    const _Float16* __restrict__ P, const float* __restrict__ gamma,
    float* __restrict__ out, int b0)
{
  __shared__ _Float16 As[2][128 * 64];
  __shared__ _Float16 Bs[2][128 * 64];

  const int tid = threadIdx.x;
  const int wid = tid >> 6, lane = tid & 63, ln = lane & 15, lh = lane >> 4;

  // XCD swizzle: 256 blocks, 32 consecutive wg per XCD (one (b,d)-panel)
  const int wg = (blockIdx.x & 7) * 32 + (blockIdx.x >> 3);
  const int bz = wg >> 7;
  const int dt = (wg >> 5) & 3;
  const int nt = wg & 31;
  const int b  = b0 + bz;
  const int d0 = dt * 128, n0 = nt * 128;

  const int wr = wid >> 1, wc = wid & 1;
  const int srow = lane >> 3;           // 0..7
  const int scol = (lane & 7) * 8;      // half offset within row

  const _Float16* Abase = Vh + (size_t)(b * C_ + d0) * N_;
  const _Float16* Bbase = P  + ((size_t)bz * N_ + n0) * N_;

  f32x4 acc[4][4] = {};

  auto stage = [&](int buf, int t) {
    const int m0 = t << 6;
    #pragma unroll
    for (int c = 0; c < 4; ++c) {
      const int row = wid * 32 + c * 8;
      g2l16(Abase + (size_t)(row + srow) * N_ + m0 + scol, &As[buf][row * 64]);
      g2l16(Bbase + (size_t)(row + srow) * N_ + m0 + scol, &Bs[buf][row * 64]);
    }
  };

  stage(0, 0);
  asm volatile("s_waitcnt vmcnt(0)" ::: "memory");
  __syncthreads();

  int cur = 0;
  for (int t = 0; t < 64; ++t) {
    if (t < 63) stage(cur ^ 1, t + 1);

    #pragma unroll
    for (int kk = 0; kk < 2; ++kk) {
      half8 a[4], bf[4];
      #pragma unroll
      for (int ft = 0; ft < 4; ++ft)
        a[ft] = *(const half8*)&As[cur][(wr * 64 + ft * 16 + ln) * 64 + kk * 32 + lh * 8];
      #pragma unroll
      for (int gt = 0; gt < 4; ++gt)
        bf[gt] = *(const half8*)&Bs[cur][(wc * 64 + gt * 16 + ln) * 64 + kk * 32 + lh * 8];
      #pragma unroll
      for (int ft = 0; ft < 4; ++ft)
        #pragma unroll
        for (int gt = 0; gt < 4; ++gt)
          acc[ft][gt] = __builtin_amdgcn_mfma_f32_16x16x32_f16(a[ft], bf[gt], acc[ft][gt], 0, 0, 0);
    }

    asm volatile("s_waitcnt vmcnt(0)" ::: "memory");
    __syncthreads();
    cur ^= 1;
  }

  const float g = gamma[0];
  #pragma unroll
  for (int ft = 0; ft < 4; ++ft) {
    #pragma unroll
    for (int gt = 0; gt < 4; ++gt) {
      #pragma unroll
      for (int j = 0; j < 4; ++j) {
        const int d = d0 + wr * 64 + ft * 16 + lh * 4 + j;
        const int n = n0 + wc * 64 + gt * 16 + ln;
        const size_t idx = ((size_t)b * C_ + d) * N_ + n;
        out[idx] = g * acc[ft][gt][j] + x[idx];
      }
    }
  }
}

extern "C" void kernel_launch(void* const* d_in, const int* in_sizes, int n_in,
                              void* d_out, int out_size, void* d_ws, size_t ws_size,
                              hipStream_t stream) {
  const float* x     = (const float*)d_in[0];
  const float* Wq    = (const float*)d_in[1];
  const float* Wk    = (const float*)d_in[2];
  const float* Wv    = (const float*)d_in[3];
  const float* gamma = (const float*)d_in[4];
  float* out = (float*)d_out;

  _Float16* Qh = (_Float16*)d_ws;                        // 2 MB
  _Float16* Kh = Qh + (size_t)B_ * N_ * CQ_;             // 2 MB
  _Float16* Vh = Kh + (size_t)B_ * N_ * CQ_;             // 16.8 MB
  float* m_g   = (float*)(Vh + (size_t)B_ * C_ * N_);    // 64 KB
  float* il_g  = m_g + (size_t)B_ * N_;                  // 64 KB
  _Float16* P  = (_Float16*)(il_g + (size_t)B_ * N_);    // 2 * N * N fp16 = 67 MB

  proj_kernel<<<dim3(64, 10, B_), 256, 0, stream>>>(x, Wq, Wk, Wv, Qh, Kh, Vh);
  stats_kernel<<<dim3(256), 512, 0, stream>>>(Qh, Kh, m_g, il_g);

  for (int pair = 0; pair < 2; ++pair) {
    pwrite_kernel<<<dim3(16, 64, 2), 256, 0, stream>>>(Qh, Kh, m_g, il_g, P, pair * 2);
    pv_kernel<<<dim3(256), 256, 0, stream>>>(x, Vh, P, gamma, out, pair * 2);
  }
}

// Round 9
// 270.001 us; speedup vs baseline: 1.6811x; 1.2992x over previous
//
#include <hip/hip_runtime.h>

#define B_  4
#define C_  512
#define CQ_ 64
#define N_  4096
#define LOG2E 1.44269504088896f

typedef _Float16 half8 __attribute__((ext_vector_type(8)));
typedef _Float16 half4 __attribute__((ext_vector_type(4)));
typedef float    f32x4 __attribute__((ext_vector_type(4)));

// async global->LDS, 16B per lane; LDS dest = wave-uniform base + lane*16
__device__ __forceinline__ void g2l16(const void* g, void* l) {
  __builtin_amdgcn_global_load_lds(
      (const __attribute__((address_space(1))) void*)g,
      (__attribute__((address_space(3))) void*)l, 16, 0, 0);
}

// ---------------------------------------------------------------------------
// Kernel 1: fused QKV projection.  Q scaled by log2e.
// XCD-chunked 1D grid: each XCD gets 320 consecutive wg = one b, 32 nBase
// tiles x 10 chTiles -> x slice (4.2 MB) stays in that XCD's L2.
// Qh[b][n][cq], Kh[b][n][cq], Vh[b][d][m]
// ---------------------------------------------------------------------------
__global__ __launch_bounds__(256) void proj_kernel(
    const float* __restrict__ x,  const float* __restrict__ Wq,
    const float* __restrict__ Wk, const float* __restrict__ Wv,
    _Float16* __restrict__ Qh, _Float16* __restrict__ Kh, _Float16* __restrict__ Vh)
{
  __shared__ _Float16 As[64][40];
  __shared__ _Float16 Bs[64][40];

  const int tid = threadIdx.x;
  const int wid = tid >> 6, lane = tid & 63, ln = lane & 15, lh = lane >> 4;

  // bijective XCD swizzle over 2560 blocks (2560/8 = 320)
  const int wg     = (blockIdx.x & 7) * 320 + (blockIdx.x >> 3);
  const int chTile = wg % 10;
  const int nBase  = ((wg / 10) & 63) * 64;
  const int b      = wg / 640;

  const float* Wsrc;
  if (chTile == 0)      Wsrc = Wq;
  else if (chTile == 1) Wsrc = Wk;
  else                  Wsrc = Wv + (size_t)(chTile - 2) * 64 * C_;

  f32x4 acc[4] = {};

  const int ar = tid >> 2, ac = (tid & 3) * 8;
  const int bc = tid >> 3, bn = (tid & 7) * 8;

  for (int kt = 0; kt < C_; kt += 32) {
    __syncthreads();
    {
      const float* src = Wsrc + (size_t)ar * C_ + kt + ac;
      #pragma unroll
      for (int u = 0; u < 8; ++u) As[ar][ac + u] = (_Float16)src[u];
    }
    {
      const float* src = x + ((size_t)b * C_ + kt + bc) * N_ + nBase + bn;
      #pragma unroll
      for (int u = 0; u < 8; ++u) Bs[bn + u][bc] = (_Float16)src[u];
    }
    __syncthreads();
    half8 a = *(const half8*)&As[wid * 16 + ln][lh * 8];
    #pragma unroll
    for (int ct = 0; ct < 4; ++ct) {
      half8 bf = *(const half8*)&Bs[ct * 16 + ln][lh * 8];
      acc[ct] = __builtin_amdgcn_mfma_f32_16x16x32_f16(a, bf, acc[ct], 0, 0, 0);
    }
  }

  #pragma unroll
  for (int ct = 0; ct < 4; ++ct) {
    const int n = nBase + ct * 16 + ln;
    #pragma unroll
    for (int j = 0; j < 4; ++j) {
      const int chL = wid * 16 + lh * 4 + j;
      if (chTile == 0)
        Qh[((size_t)b * N_ + n) * CQ_ + chL] = (_Float16)(acc[ct][j] * LOG2E);
      else if (chTile == 1)
        Kh[((size_t)b * N_ + n) * CQ_ + chL] = (_Float16)acc[ct][j];
      else
        Vh[((size_t)b * C_ + (chTile - 2) * 64 + chL) * N_ + n] = (_Float16)acc[ct][j];
    }
  }
}

// ---------------------------------------------------------------------------
// Kernel 2: exact softmax stats (log2 domain): per-row max m and 1/l.
// Swapped mfma(K,Q), online (m,s) per thread, no loop barriers.
// Same 2-MFMA chain as the P-writer, so e-m <= ~0 there.
// ---------------------------------------------------------------------------
__global__ __launch_bounds__(512, 2) void stats_kernel(
    const _Float16* __restrict__ Qh, const _Float16* __restrict__ Kh,
    float* __restrict__ m_g, float* __restrict__ il_g)
{
  __shared__ float Ms[8][64];
  __shared__ float Ss[8][64];

  const int tid = threadIdx.x;
  const int wid = tid >> 6, lane = tid & 63, ln = lane & 15, lh = lane >> 4;
  const int b  = blockIdx.x >> 6;
  const int qb = (blockIdx.x & 63) * 64;

  half8 qf[4][2];
  #pragma unroll
  for (int rt = 0; rt < 4; ++rt)
    #pragma unroll
    for (int h = 0; h < 2; ++h)
      qf[rt][h] = *(const half8*)&Qh[((size_t)b * N_ + qb + rt * 16 + ln) * CQ_ + h * 32 + lh * 8];

  float mx[4] = {-3.0e38f, -3.0e38f, -3.0e38f, -3.0e38f};
  float sm[4] = {0.f, 0.f, 0.f, 0.f};

  const _Float16* kp = Kh + ((size_t)b * N_ + wid * 16 + ln) * CQ_ + lh * 8;

  for (int it = 0; it < 32; ++it) {
    const _Float16* kq = kp + (size_t)(it * 128) * CQ_;
    half8 k0 = *(const half8*)kq;
    half8 k1 = *(const half8*)(kq + 32);
    #pragma unroll
    for (int rt = 0; rt < 4; ++rt) {
      f32x4 e = {};
      e = __builtin_amdgcn_mfma_f32_16x16x32_f16(k0, qf[rt][0], e, 0, 0, 0);
      e = __builtin_amdgcn_mfma_f32_16x16x32_f16(k1, qf[rt][1], e, 0, 0, 0);
      const float m1 = fmaxf(fmaxf(e[0], e[1]), fmaxf(e[2], e[3]));
      const float mn = fmaxf(mx[rt], m1);
      sm[rt] = sm[rt] * exp2f(mx[rt] - mn)
             + exp2f(e[0] - mn) + exp2f(e[1] - mn)
             + exp2f(e[2] - mn) + exp2f(e[3] - mn);
      mx[rt] = mn;
    }
  }

  #pragma unroll
  for (int rt = 0; rt < 4; ++rt) {
    float m = mx[rt], s = sm[rt];
    #pragma unroll
    for (int mask = 16; mask <= 32; mask <<= 1) {
      const float om = __shfl_xor(m, mask);
      const float os = __shfl_xor(s, mask);
      const float mn = fmaxf(m, om);
      s = s * exp2f(m - mn) + os * exp2f(om - mn);
      m = mn;
    }
    if (lane < 16) { Ms[wid][rt * 16 + lane] = m; Ss[wid][rt * 16 + lane] = s; }
  }
  __syncthreads();
  if (tid < 64) {
    float m = Ms[0][tid], s = Ss[0][tid];
    #pragma unroll
    for (int w = 1; w < 8; ++w) {
      const float om = Ms[w][tid], os = Ss[w][tid];
      const float mn = fmaxf(m, om);
      s = s * exp2f(m - mn) + os * exp2f(om - mn);
      m = mn;
    }
    m_g[(size_t)b * N_ + qb + tid]  = m;
    il_g[(size_t)b * N_ + qb + tid] = 1.0f / s;
  }
}

// ---------------------------------------------------------------------------
// Kernel 3: P-writer.  P[bz][q][m] = exp2(e - m_q) * il_q  (fp16, normalized).
// Block = 64 q x 256 m. MFMA results land in padded LDS, then stored with
// full coalescing (16B/lane over 64B segments).
// ---------------------------------------------------------------------------
__global__ __launch_bounds__(256) void pwrite_kernel(
    const _Float16* __restrict__ Qh, const _Float16* __restrict__ Kh,
    const float* __restrict__ m_g, const float* __restrict__ il_g,
    _Float16* __restrict__ P, int b0)
{
  __shared__ _Float16 Pl[64 * 260];   // 33 KB, pad 260 (rows 2 banks apart)

  const int tid = threadIdx.x;
  const int wid = tid >> 6, lane = tid & 63, ln = lane & 15, lh = lane >> 4;
  const int mb = blockIdx.x * 256;
  const int qb = blockIdx.y * 64;
  const int bz = blockIdx.z;
  const int b  = b0 + bz;

  float m_l[4], il_l[4];
  #pragma unroll
  for (int rt = 0; rt < 4; ++rt) {
    m_l[rt]  = m_g [(size_t)b * N_ + qb + rt * 16 + ln];
    il_l[rt] = il_g[(size_t)b * N_ + qb + rt * 16 + ln];
  }

  half8 qf[4][2];
  #pragma unroll
  for (int rt = 0; rt < 4; ++rt)
    #pragma unroll
    for (int h = 0; h < 2; ++h)
      qf[rt][h] = *(const half8*)&Qh[((size_t)b * N_ + qb + rt * 16 + ln) * CQ_ + h * 32 + lh * 8];

  half8 kf[4][2];
  #pragma unroll
  for (int ms = 0; ms < 4; ++ms)
    #pragma unroll
    for (int h = 0; h < 2; ++h)
      kf[ms][h] = *(const half8*)&Kh[((size_t)b * N_ + mb + wid * 64 + ms * 16 + ln) * CQ_ + h * 32 + lh * 8];

  #pragma unroll
  for (int ms = 0; ms < 4; ++ms) {
    #pragma unroll
    for (int rt = 0; rt < 4; ++rt) {
      f32x4 e = {};
      e = __builtin_amdgcn_mfma_f32_16x16x32_f16(kf[ms][0], qf[rt][0], e, 0, 0, 0);
      e = __builtin_amdgcn_mfma_f32_16x16x32_f16(kf[ms][1], qf[rt][1], e, 0, 0, 0);
      half4 pv;
      #pragma unroll
      for (int j = 0; j < 4; ++j)
        pv[j] = (_Float16)(exp2f(e[j] - m_l[rt]) * il_l[rt]);
      *(half4*)&Pl[(rt * 16 + ln) * 260 + wid * 64 + ms * 16 + lh * 4] = pv;
    }
  }
  __syncthreads();

  // coalesced store: thread t -> row t>>2, 8 chunks of 16B
  const int row = tid >> 2;
  const int cb  = (tid & 3) * 8;   // halfs
  #pragma unroll
  for (int i = 0; i < 8; ++i) {
    half8 v = *(const half8*)&Pl[row * 260 + cb + i * 32];
    *(half8*)&P[((size_t)bz * N_ + qb + row) * N_ + mb + cb + i * 32] = v;
  }
}

// ---------------------------------------------------------------------------
// Kernel 4: PV GEMM.  out[b][d][n] = g * (V . P^T) + x.
// Tile 256d x 128n, BK=64, 8 waves (wave = 64d x 64n), double-buffered
// linear LDS (96 KB) via global_load_lds(16B), 2-phase loop (T3 minimum):
// stage(next) || ds_read+MFMA(cur) -> vmcnt(0) -> barrier.
// dt innermost in the XCD chunk so the 2 blocks sharing a P panel are
// adjacent (L2 reuse); P fetched <= 2x instead of 4x.
// ---------------------------------------------------------------------------
__global__ __launch_bounds__(512) void pv_kernel(
    const float* __restrict__ x, const _Float16* __restrict__ Vh,
    const _Float16* __restrict__ P, const float* __restrict__ gamma,
    float* __restrict__ out, int b0, int nwg)
{
  __shared__ _Float16 As[2][256 * 64];   // 32 KB x2
  __shared__ _Float16 Bs[2][128 * 64];   // 16 KB x2

  const int tid = threadIdx.x;
  const int wid = tid >> 6, lane = tid & 63, ln = lane & 15, lh = lane >> 4;

  // bijective XCD swizzle (nwg % 8 == 0)
  const int q8 = nwg >> 3;
  const int wg = (blockIdx.x & 7) * q8 + (blockIdx.x >> 3);
  const int dt = wg & 1;
  const int nt = (wg >> 1) & 31;
  const int bz = wg >> 6;
  const int b  = b0 + bz;
  const int d0 = dt * 256, n0 = nt * 128;

  const _Float16* Ab = Vh + ((size_t)b * C_ + d0) * N_;
  const _Float16* Bb = P  + ((size_t)bz * N_ + n0) * N_;

  const int wr = wid >> 1, wc = wid & 1;   // wave = 64d x 64n
  f32x4 acc[4][4] = {};

  const int Sw = wid * 1024 + lane * 16;   // per-thread staging byte offset

  auto stage = [&](int buf, int t) {
    const int m0 = t << 6;
    #pragma unroll
    for (int r = 0; r < 4; ++r) {           // As: 32 KB = 4 rounds x 8 KB
      const int S = r * 8192 + Sw;
      const int row = S >> 7, colb = S & 127;
      g2l16((const char*)(Ab + (size_t)row * N_ + m0) + colb,
            (char*)&As[buf][0] + r * 8192 + wid * 1024);
    }
    #pragma unroll
    for (int r = 0; r < 2; ++r) {           // Bs: 16 KB = 2 rounds
      const int S = r * 8192 + Sw;
      const int row = S >> 7, colb = S & 127;
      g2l16((const char*)(Bb + (size_t)row * N_ + m0) + colb,
            (char*)&Bs[buf][0] + r * 8192 + wid * 1024);
    }
  };

  stage(0, 0);
  asm volatile("s_waitcnt vmcnt(0)" ::: "memory");
  __syncthreads();

  int cur = 0;
  for (int t = 0; t < 64; ++t) {
    if (t < 63) stage(cur ^ 1, t + 1);

    #pragma unroll
    for (int kk = 0; kk < 2; ++kk) {
      half8 a[4], bf[4];
      #pragma unroll
      for (int ft = 0; ft < 4; ++ft)
        a[ft] = *(const half8*)&As[cur][(wr * 64 + ft * 16 + ln) * 64 + kk * 32 + lh * 8];
      #pragma unroll
      for (int gt = 0; gt < 4; ++gt)
        bf[gt] = *(const half8*)&Bs[cur][(wc * 64 + gt * 16 + ln) * 64 + kk * 32 + lh * 8];
      #pragma unroll
      for (int ft = 0; ft < 4; ++ft)
        #pragma unroll
        for (int gt = 0; gt < 4; ++gt)
          acc[ft][gt] = __builtin_amdgcn_mfma_f32_16x16x32_f16(a[ft], bf[gt], acc[ft][gt], 0, 0, 0);
    }

    asm volatile("s_waitcnt vmcnt(0)" ::: "memory");
    __syncthreads();
    cur ^= 1;
  }

  const float g = gamma[0];
  #pragma unroll
  for (int ft = 0; ft < 4; ++ft) {
    #pragma unroll
    for (int gt = 0; gt < 4; ++gt) {
      #pragma unroll
      for (int j = 0; j < 4; ++j) {
        const int d = d0 + wr * 64 + ft * 16 + lh * 4 + j;
        const int n = n0 + wc * 64 + gt * 16 + ln;
        const size_t idx = ((size_t)b * C_ + d) * N_ + n;
        out[idx] = g * acc[ft][gt][j] + x[idx];
      }
    }
  }
}

extern "C" void kernel_launch(void* const* d_in, const int* in_sizes, int n_in,
                              void* d_out, int out_size, void* d_ws, size_t ws_size,
                              hipStream_t stream) {
  const float* x     = (const float*)d_in[0];
  const float* Wq    = (const float*)d_in[1];
  const float* Wk    = (const float*)d_in[2];
  const float* Wv    = (const float*)d_in[3];
  const float* gamma = (const float*)d_in[4];
  float* out = (float*)d_out;

  _Float16* Qh = (_Float16*)d_ws;                        // 2 MB
  _Float16* Kh = Qh + (size_t)B_ * N_ * CQ_;             // 2 MB
  _Float16* Vh = Kh + (size_t)B_ * N_ * CQ_;             // 16.8 MB
  float* m_g   = (float*)(Vh + (size_t)B_ * C_ * N_);    // 64 KB
  float* il_g  = m_g + (size_t)B_ * N_;                  // 64 KB
  _Float16* P  = (_Float16*)(il_g + (size_t)B_ * N_);

  const size_t base  = (size_t)(2 + 2 + 16) * 1024 * 1024 + (size_t)16 * 1024 * 1024 / 16 + (size_t)256 * 1024;
  const size_t fixed = ((char*)P - (char*)d_ws);
  const int nb = (ws_size >= fixed + (size_t)B_ * N_ * N_ * sizeof(_Float16)) ? 4 : 2;
  (void)base;

  proj_kernel<<<dim3(2560), 256, 0, stream>>>(x, Wq, Wk, Wv, Qh, Kh, Vh);
  stats_kernel<<<dim3(256), 512, 0, stream>>>(Qh, Kh, m_g, il_g);

  for (int b0 = 0; b0 < B_; b0 += nb) {
    pwrite_kernel<<<dim3(16, 64, nb), 256, 0, stream>>>(Qh, Kh, m_g, il_g, P, b0);
    pv_kernel<<<dim3(nb * 64), 512, 0, stream>>>(x, Vh, P, gamma, out, b0, nb * 64);
  }
}

// Round 10
// 236.978 us; speedup vs baseline: 1.9154x; 1.1393x over previous
//
#include <hip/hip_runtime.h>

#define B_  4
#define C_  512
#define CQ_ 64
#define N_  4096
#define LOG2E 1.44269504088896f

typedef _Float16 half8 __attribute__((ext_vector_type(8)));
typedef _Float16 half4 __attribute__((ext_vector_type(4)));
typedef float    f32x4 __attribute__((ext_vector_type(4)));

// async global->LDS, 16B per lane; LDS dest = wave-uniform base + lane*16
__device__ __forceinline__ void g2l16(const void* g, void* l) {
  __builtin_amdgcn_global_load_lds(
      (const __attribute__((address_space(1))) void*)g,
      (__attribute__((address_space(3))) void*)l, 16, 0, 0);
}

// ---------------------------------------------------------------------------
// Kernel 0: W -> fp16 (Wq rows pre-scaled by log2e).  Wh[640][512].
// Rows [0,64)=Wq, [64,128)=Wk, [128,640)=Wv.  0.65 MB -> L2-resident.
// ---------------------------------------------------------------------------
__global__ __launch_bounds__(256) void wcvt_kernel(
    const float* __restrict__ Wq, const float* __restrict__ Wk,
    const float* __restrict__ Wv, _Float16* __restrict__ Wh)
{
  const int row = blockIdx.x;
  const float* src;
  float s = 1.0f;
  if (row < 64)       { src = Wq + (size_t)row * C_; s = LOG2E; }
  else if (row < 128) { src = Wk + (size_t)(row - 64) * C_; }
  else                { src = Wv + (size_t)(row - 128) * C_; }
  for (int c = threadIdx.x; c < C_; c += 256)
    Wh[(size_t)row * C_ + c] = (_Float16)(src[c] * s);
}

// ---------------------------------------------------------------------------
// Kernel 1: fused QKV projection, x staged ONCE per block.
// Block = (b, 64 n); x tile (64n x 512c) -> padded LDS; loop 10 chTiles
// reading W fragments straight from fp16 Wh (L2).  One barrier total.
// Qh[b][n][cq] (log2e folded via Wh), Kh[b][n][cq], Vh[b][d][m]
// ---------------------------------------------------------------------------
__global__ __launch_bounds__(256) void proj_kernel(
    const float* __restrict__ x, const _Float16* __restrict__ Wh,
    _Float16* __restrict__ Qh, _Float16* __restrict__ Kh, _Float16* __restrict__ Vh)
{
  __shared__ _Float16 xs[64][520];   // 66.6 KB, pad 8 halfs

  const int tid = threadIdx.x;
  const int wid = tid >> 6, lane = tid & 63, ln = lane & 15, lh = lane >> 4;

  // bijective XCD swizzle: 256 blocks, 32 consecutive wg per XCD
  const int wg = (blockIdx.x & 7) * 32 + (blockIdx.x >> 3);
  const int b  = wg >> 6;
  const int n0 = (wg & 63) * 64;

  // ---- stage x tile (fp32 -> fp16, transpose to [n][c])
  {
    const int nn = (tid & 15) * 4;
    const int c0 = tid >> 4;
    #pragma unroll 4
    for (int cc = 0; cc < 32; ++cc) {
      const int c = cc * 16 + c0;
      f32x4 v = *(const f32x4*)&x[((size_t)b * C_ + c) * N_ + n0 + nn];
      #pragma unroll
      for (int u = 0; u < 4; ++u) xs[nn + u][c] = (_Float16)v[u];
    }
  }
  __syncthreads();

  for (int chT = 0; chT < 10; ++chT) {
    f32x4 acc[4] = {};
    const _Float16* wrow = Wh + (size_t)(chT * 64 + wid * 16 + ln) * C_;

    #pragma unroll 4
    for (int kt = 0; kt < C_; kt += 32) {
      half8 a = *(const half8*)&wrow[kt + lh * 8];
      #pragma unroll
      for (int ct = 0; ct < 4; ++ct) {
        half8 bf = *(const half8*)&xs[ct * 16 + ln][kt + lh * 8];
        acc[ct] = __builtin_amdgcn_mfma_f32_16x16x32_f16(a, bf, acc[ct], 0, 0, 0);
      }
    }

    #pragma unroll
    for (int ct = 0; ct < 4; ++ct) {
      const int n = n0 + ct * 16 + ln;
      #pragma unroll
      for (int j = 0; j < 4; ++j) {
        const int chL = wid * 16 + lh * 4 + j;
        const _Float16 v = (_Float16)acc[ct][j];
        if (chT == 0)      Qh[((size_t)b * N_ + n) * CQ_ + chL] = v;
        else if (chT == 1) Kh[((size_t)b * N_ + n) * CQ_ + chL] = v;
        else               Vh[((size_t)b * C_ + (chT - 2) * 64 + chL) * N_ + n] = v;
      }
    }
  }
}

// ---------------------------------------------------------------------------
// Kernel 2: exact softmax stats (log2 domain): per-row max m and 1/l.
// Swapped mfma(K,Q), online (m,s) per thread, no loop barriers.
// Same 2-MFMA chain as the P-writer, so e-m <= ~0 there.
// ---------------------------------------------------------------------------
__global__ __launch_bounds__(512, 2) void stats_kernel(
    const _Float16* __restrict__ Qh, const _Float16* __restrict__ Kh,
    float* __restrict__ m_g, float* __restrict__ il_g)
{
  __shared__ float Ms[8][64];
  __shared__ float Ss[8][64];

  const int tid = threadIdx.x;
  const int wid = tid >> 6, lane = tid & 63, ln = lane & 15, lh = lane >> 4;
  const int b  = blockIdx.x >> 6;
  const int qb = (blockIdx.x & 63) * 64;

  half8 qf[4][2];
  #pragma unroll
  for (int rt = 0; rt < 4; ++rt)
    #pragma unroll
    for (int h = 0; h < 2; ++h)
      qf[rt][h] = *(const half8*)&Qh[((size_t)b * N_ + qb + rt * 16 + ln) * CQ_ + h * 32 + lh * 8];

  float mx[4] = {-3.0e38f, -3.0e38f, -3.0e38f, -3.0e38f};
  float sm[4] = {0.f, 0.f, 0.f, 0.f};

  const _Float16* kp = Kh + ((size_t)b * N_ + wid * 16 + ln) * CQ_ + lh * 8;

  for (int it = 0; it < 32; ++it) {
    const _Float16* kq = kp + (size_t)(it * 128) * CQ_;
    half8 k0 = *(const half8*)kq;
    half8 k1 = *(const half8*)(kq + 32);
    #pragma unroll
    for (int rt = 0; rt < 4; ++rt) {
      f32x4 e = {};
      e = __builtin_amdgcn_mfma_f32_16x16x32_f16(k0, qf[rt][0], e, 0, 0, 0);
      e = __builtin_amdgcn_mfma_f32_16x16x32_f16(k1, qf[rt][1], e, 0, 0, 0);
      const float m1 = fmaxf(fmaxf(e[0], e[1]), fmaxf(e[2], e[3]));
      const float mn = fmaxf(mx[rt], m1);
      sm[rt] = sm[rt] * exp2f(mx[rt] - mn)
             + exp2f(e[0] - mn) + exp2f(e[1] - mn)
             + exp2f(e[2] - mn) + exp2f(e[3] - mn);
      mx[rt] = mn;
    }
  }

  #pragma unroll
  for (int rt = 0; rt < 4; ++rt) {
    float m = mx[rt], s = sm[rt];
    #pragma unroll
    for (int mask = 16; mask <= 32; mask <<= 1) {
      const float om = __shfl_xor(m, mask);
      const float os = __shfl_xor(s, mask);
      const float mn = fmaxf(m, om);
      s = s * exp2f(m - mn) + os * exp2f(om - mn);
      m = mn;
    }
    if (lane < 16) { Ms[wid][rt * 16 + lane] = m; Ss[wid][rt * 16 + lane] = s; }
  }
  __syncthreads();
  if (tid < 64) {
    float m = Ms[0][tid], s = Ss[0][tid];
    #pragma unroll
    for (int w = 1; w < 8; ++w) {
      const float om = Ms[w][tid], os = Ss[w][tid];
      const float mn = fmaxf(m, om);
      s = s * exp2f(m - mn) + os * exp2f(om - mn);
      m = mn;
    }
    m_g[(size_t)b * N_ + qb + tid]  = m;
    il_g[(size_t)b * N_ + qb + tid] = 1.0f / s;
  }
}

// ---------------------------------------------------------------------------
// Kernel 3: P-writer.  P[bz][q][m] = exp2(e - m_q) * il_q  (fp16, normalized).
// Block = 64 q x 256 m; MFMA results -> padded LDS -> coalesced 16B stores.
// ---------------------------------------------------------------------------
__global__ __launch_bounds__(256) void pwrite_kernel(
    const _Float16* __restrict__ Qh, const _Float16* __restrict__ Kh,
    const float* __restrict__ m_g, const float* __restrict__ il_g,
    _Float16* __restrict__ P, int b0)
{
  __shared__ _Float16 Pl[64 * 260];

  const int tid = threadIdx.x;
  const int wid = tid >> 6, lane = tid & 63, ln = lane & 15, lh = lane >> 4;
  const int mb = blockIdx.x * 256;
  const int qb = blockIdx.y * 64;
  const int bz = blockIdx.z;
  const int b  = b0 + bz;

  float m_l[4], il_l[4];
  #pragma unroll
  for (int rt = 0; rt < 4; ++rt) {
    m_l[rt]  = m_g [(size_t)b * N_ + qb + rt * 16 + ln];
    il_l[rt] = il_g[(size_t)b * N_ + qb + rt * 16 + ln];
  }

  half8 qf[4][2];
  #pragma unroll
  for (int rt = 0; rt < 4; ++rt)
    #pragma unroll
    for (int h = 0; h < 2; ++h)
      qf[rt][h] = *(const half8*)&Qh[((size_t)b * N_ + qb + rt * 16 + ln) * CQ_ + h * 32 + lh * 8];

  half8 kf[4][2];
  #pragma unroll
  for (int ms = 0; ms < 4; ++ms)
    #pragma unroll
    for (int h = 0; h < 2; ++h)
      kf[ms][h] = *(const half8*)&Kh[((size_t)b * N_ + mb + wid * 64 + ms * 16 + ln) * CQ_ + h * 32 + lh * 8];

  #pragma unroll
  for (int ms = 0; ms < 4; ++ms) {
    #pragma unroll
    for (int rt = 0; rt < 4; ++rt) {
      f32x4 e = {};
      e = __builtin_amdgcn_mfma_f32_16x16x32_f16(kf[ms][0], qf[rt][0], e, 0, 0, 0);
      e = __builtin_amdgcn_mfma_f32_16x16x32_f16(kf[ms][1], qf[rt][1], e, 0, 0, 0);
      half4 pv;
      #pragma unroll
      for (int j = 0; j < 4; ++j)
        pv[j] = (_Float16)(exp2f(e[j] - m_l[rt]) * il_l[rt]);
      *(half4*)&Pl[(rt * 16 + ln) * 260 + wid * 64 + ms * 16 + lh * 4] = pv;
    }
  }
  __syncthreads();

  const int row = tid >> 2;
  const int cb  = (tid & 3) * 8;
  #pragma unroll
  for (int i = 0; i < 8; ++i) {
    half8 v = *(const half8*)&Pl[row * 260 + cb + i * 32];
    *(half8*)&P[((size_t)bz * N_ + qb + row) * N_ + mb + cb + i * 32] = v;
  }
}

// ---------------------------------------------------------------------------
// Kernel 4: PV GEMM, m97 geometry.  out[b][d][n] = g * (V . P^T) + x.
// 128d x 128n tile, BK=64, 256 thr (4 waves 2x2, wave 64x64), double-buffered
// 64 KB LDS -> 2 blocks/CU.  T2 swizzle via pre-swizzled global source
// (chunk ^= row&7) + swizzled ds_read; LDS dest stays linear (rule #21).
// 2-phase loop: stage(next) || MFMA(cur) -> vmcnt(0) -> barrier.
// ---------------------------------------------------------------------------
__global__ __launch_bounds__(256) void pv_kernel(
    const float* __restrict__ x, const _Float16* __restrict__ Vh,
    const _Float16* __restrict__ P, const float* __restrict__ gamma,
    float* __restrict__ out, int b0, int nwg)
{
  __shared__ _Float16 As[2][128 * 64];   // 16 KB x2
  __shared__ _Float16 Bs[2][128 * 64];   // 16 KB x2

  const int tid = threadIdx.x;
  const int wid = tid >> 6, lane = tid & 63, ln = lane & 15, lh = lane >> 4;

  // bijective XCD swizzle (nwg % 8 == 0): consecutive wg share bz + V panels
  const int q8 = nwg >> 3;
  const int wg = (blockIdx.x & 7) * q8 + (blockIdx.x >> 3);
  const int nt = wg & 31;
  const int dt = (wg >> 5) & 3;
  const int bz = wg >> 7;
  const int b  = b0 + bz;
  const int d0 = dt * 128, n0 = nt * 128;

  const _Float16* Ab = Vh + ((size_t)b * C_ + d0) * N_;
  const _Float16* Bb = P  + ((size_t)bz * N_ + n0) * N_;

  const int wr = wid >> 1, wc = wid & 1;
  f32x4 acc[4][4] = {};

  // staging geometry: per round, wave covers 8 rows (1 KB); 4 rounds = 128 rows
  const int srow = lane >> 3;                      // row within wave's 8
  const int schunk = lane & 7;                     // LDS 16B chunk within row
  auto stage = [&](int buf, int t) {
    const int m0 = t << 6;
    #pragma unroll
    for (int r = 0; r < 4; ++r) {
      const int row = r * 32 + wid * 8 + srow;
      const int csw = (schunk ^ (row & 7)) << 3;   // pre-swizzled source chunk
      g2l16(Ab + (size_t)row * N_ + m0 + csw,
            (char*)&As[buf][0] + r * 4096 + wid * 1024);
      g2l16(Bb + (size_t)row * N_ + m0 + csw,
            (char*)&Bs[buf][0] + r * 4096 + wid * 1024);
    }
  };

  stage(0, 0);
  asm volatile("s_waitcnt vmcnt(0)" ::: "memory");
  __syncthreads();

  const int swl = ln & 7;
  int cur = 0;
  for (int t = 0; t < 64; ++t) {
    if (t < 63) stage(cur ^ 1, t + 1);

    #pragma unroll
    for (int kk = 0; kk < 2; ++kk) {
      half8 a[4], bf[4];
      #pragma unroll
      for (int ft = 0; ft < 4; ++ft) {
        const int row = wr * 64 + ft * 16 + ln;
        a[ft] = *(const half8*)&As[cur][row * 64 + ((((kk << 2) | lh) ^ swl) << 3)];
      }
      #pragma unroll
      for (int gt = 0; gt < 4; ++gt) {
        const int row = wc * 64 + gt * 16 + ln;
        bf[gt] = *(const half8*)&Bs[cur][row * 64 + ((((kk << 2) | lh) ^ swl) << 3)];
      }
      #pragma unroll
      for (int ft = 0; ft < 4; ++ft)
        #pragma unroll
        for (int gt = 0; gt < 4; ++gt)
          acc[ft][gt] = __builtin_amdgcn_mfma_f32_16x16x32_f16(a[ft], bf[gt], acc[ft][gt], 0, 0, 0);
    }

    asm volatile("s_waitcnt vmcnt(0)" ::: "memory");
    __syncthreads();
    cur ^= 1;
  }

  const float g = gamma[0];
  #pragma unroll
  for (int ft = 0; ft < 4; ++ft) {
    #pragma unroll
    for (int gt = 0; gt < 4; ++gt) {
      #pragma unroll
      for (int j = 0; j < 4; ++j) {
        const int d = d0 + wr * 64 + ft * 16 + lh * 4 + j;
        const int n = n0 + wc * 64 + gt * 16 + ln;
        const size_t idx = ((size_t)b * C_ + d) * N_ + n;
        out[idx] = g * acc[ft][gt][j] + x[idx];
      }
    }
  }
}

extern "C" void kernel_launch(void* const* d_in, const int* in_sizes, int n_in,
                              void* d_out, int out_size, void* d_ws, size_t ws_size,
                              hipStream_t stream) {
  const float* x     = (const float*)d_in[0];
  const float* Wq    = (const float*)d_in[1];
  const float* Wk    = (const float*)d_in[2];
  const float* Wv    = (const float*)d_in[3];
  const float* gamma = (const float*)d_in[4];
  float* out = (float*)d_out;

  _Float16* Qh = (_Float16*)d_ws;                        // 2 MB
  _Float16* Kh = Qh + (size_t)B_ * N_ * CQ_;             // 2 MB
  _Float16* Vh = Kh + (size_t)B_ * N_ * CQ_;             // 16.8 MB
  float* m_g   = (float*)(Vh + (size_t)B_ * C_ * N_);    // 64 KB
  float* il_g  = m_g + (size_t)B_ * N_;                  // 64 KB
  _Float16* Wh = (_Float16*)(il_g + (size_t)B_ * N_);    // 0.66 MB
  _Float16* P  = Wh + (size_t)640 * C_;

  const size_t fixed = (size_t)((char*)P - (char*)d_ws);
  const int nb = (ws_size >= fixed + (size_t)B_ * N_ * N_ * sizeof(_Float16)) ? 4 : 2;

  wcvt_kernel<<<dim3(640), 256, 0, stream>>>(Wq, Wk, Wv, Wh);
  proj_kernel<<<dim3(256), 256, 0, stream>>>(x, Wh, Qh, Kh, Vh);
  stats_kernel<<<dim3(256), 512, 0, stream>>>(Qh, Kh, m_g, il_g);

  for (int b0 = 0; b0 < B_; b0 += nb) {
    pwrite_kernel<<<dim3(16, 64, nb), 256, 0, stream>>>(Qh, Kh, m_g, il_g, P, b0);
    pv_kernel<<<dim3(nb * 128), 256, 0, stream>>>(x, Vh, P, gamma, out, b0, nb * 128);
  }
}